// Round 2
// baseline (859.129 us; speedup 1.0000x reference)
//
#include <hip/hip_runtime.h>
#include <math.h>

#define B_ 16
#define H_ 96
#define W_ 96
#define C_ 128
#define HW_ (H_*W_)            // 9216
#define NTOK (B_*HW_)          // 147456
#define NOUT 260

typedef unsigned short ushort_t;

__device__ __forceinline__ float gelu_f(float t) {
    return 0.5f * t * (1.0f + erff(t * 0.7071067811865475f));
}
__device__ __forceinline__ float b2f(ushort_t u) {
    union { unsigned int i; float f; } t; t.i = (unsigned int)u << 16; return t.f;
}
__device__ __forceinline__ ushort_t f2b(float f) {
    union { float f; unsigned int i; } t; t.f = f;
    unsigned int lsb = (t.i >> 16) & 1u;
    t.i += 0x7fffu + lsb;            // round-to-nearest-even
    return (ushort_t)(t.i >> 16);
}

// ---------------------------------------------------------------------------
// K1: ctx = (x @ Wf)[:, 128:256] + bf ; gates = (x @ Wf)[:, 256:260] + bf
// block = 256, M-tile = 64 tokens. ctx stored bf16.
// ---------------------------------------------------------------------------
__global__ __launch_bounds__(256) void gemm_ctx_gates(
    const float* __restrict__ x, const float* __restrict__ Wf,
    const float* __restrict__ bf,
    ushort_t* __restrict__ ctx, float* __restrict__ gates)
{
    __shared__ float As[128][64];   // [k][m]  32 KB
    __shared__ float Bs[128][64];   // [k][n]  32 KB
    const int tid  = threadIdx.x;
    const int tok0 = blockIdx.x * 64;
    const int t    = tid & 63;
    const int k4   = (tid >> 6) << 2;

    {   // x tile transposed into As[k][t]
        const float* xp = x + (size_t)(tok0 + t) * C_;
        #pragma unroll
        for (int kk = k4; kk < C_; kk += 16) {
            float4 v = *(const float4*)(xp + kk);
            As[kk+0][t] = v.x; As[kk+1][t] = v.y;
            As[kk+2][t] = v.z; As[kk+3][t] = v.w;
        }
    }

    const int tx = tid & 15;
    const int ty = tid >> 4;
    const int n4 = tx << 2;

    for (int chunk = 0; chunk < 2; ++chunk) {
        const int n0 = C_ + (chunk << 6);     // Wf cols 128..191, 192..255
        __syncthreads();
        #pragma unroll
        for (int kk = ty; kk < C_; kk += 16)
            *(float4*)&Bs[kk][n4] = *(const float4*)(Wf + (size_t)kk * NOUT + n0 + n4);
        __syncthreads();

        float acc[16] = {};
        #pragma unroll 4
        for (int k = 0; k < C_; ++k) {
            const float4 a = *(const float4*)&As[k][ty << 2];
            const float4 b = *(const float4*)&Bs[k][n4];
            const float av[4] = {a.x, a.y, a.z, a.w};
            const float bv[4] = {b.x, b.y, b.z, b.w};
            #pragma unroll
            for (int i = 0; i < 4; ++i)
                #pragma unroll
                for (int j = 0; j < 4; ++j)
                    acc[i*4+j] += av[i] * bv[j];
        }

        const int col = (n0 - C_) + n4;       // 0..255 within ctx
        const float4 bias = *(const float4*)(bf + n0 + n4);
        #pragma unroll
        for (int i = 0; i < 4; ++i) {
            const int token = tok0 + (ty << 2) + i;
            ushort4 r;
            r.x = f2b(acc[i*4+0] + bias.x);
            r.y = f2b(acc[i*4+1] + bias.y);
            r.z = f2b(acc[i*4+2] + bias.z);
            r.w = f2b(acc[i*4+3] + bias.w);
            *(ushort4*)(ctx + (size_t)token * C_ + col) = r;
        }
    }

    {   // gates: cols 256..259
        const int tt = tid & 63;
        const int g  = tid >> 6;
        float s = 0.f;
        #pragma unroll 8
        for (int k = 0; k < C_; ++k)
            s += As[k][tt] * Wf[(size_t)k * NOUT + 2*C_ + g];
        gates[(size_t)(tok0 + tt) * 4 + g] = s + bf[2*C_ + g];
    }
}

// ---------------------------------------------------------------------------
// K2: depthwise conv (SAME) + gelu + gated accumulate into ctx_all (bf16)
// ---------------------------------------------------------------------------
template<int KS>
__global__ __launch_bounds__(256) void dwconv_k(
    const ushort_t* __restrict__ in, const float* __restrict__ wk,
    const float* __restrict__ gates, ushort_t* __restrict__ out,
    ushort_t* __restrict__ ctx_all, const int level)
{
    const int gtid = blockIdx.x * 256 + threadIdx.x;
    const int c4   = (gtid & 31) << 2;
    const int pix  = gtid >> 5;
    if (pix >= NTOK) return;
    const int w = pix % W_;
    const int h = (pix / W_) % H_;
    const int R = KS >> 1;

    float ax = 0.f, ay = 0.f, az = 0.f, aw = 0.f;
    #pragma unroll
    for (int kh = 0; kh < KS; ++kh) {
        const int hh = h + kh - R;
        if (hh < 0 || hh >= H_) continue;
        #pragma unroll
        for (int kw = 0; kw < KS; ++kw) {
            const int ww = w + kw - R;
            if (ww < 0 || ww >= W_) continue;
            const ushort4 v = *(const ushort4*)(in + (size_t)(pix + (kh-R)*W_ + (kw-R)) * C_ + c4);
            const float4 kv = *(const float4*)(wk + (size_t)(kh*KS + kw) * C_ + c4);
            ax += b2f(v.x) * kv.x; ay += b2f(v.y) * kv.y;
            az += b2f(v.z) * kv.z; aw += b2f(v.w) * kv.w;
        }
    }
    const float gx = gelu_f(ax), gy = gelu_f(ay), gz = gelu_f(az), gw = gelu_f(aw);
    ushort4 o; o.x = f2b(gx); o.y = f2b(gy); o.z = f2b(gz); o.w = f2b(gw);
    *(ushort4*)(out + (size_t)pix * C_ + c4) = o;

    const float gate = gates[(size_t)pix * 4 + level];
    ushort_t* ap = ctx_all + (size_t)pix * C_ + c4;
    if (level == 0) {
        ushort4 r;
        r.x = f2b(gx * gate); r.y = f2b(gy * gate);
        r.z = f2b(gz * gate); r.w = f2b(gw * gate);
        *(ushort4*)ap = r;
    } else {
        ushort4 p = *(const ushort4*)ap;
        ushort4 r;
        r.x = f2b(b2f(p.x) + gx * gate); r.y = f2b(b2f(p.y) + gy * gate);
        r.z = f2b(b2f(p.z) + gz * gate); r.w = f2b(b2f(p.w) + gw * gate);
        *(ushort4*)ap = r;
    }
}

// ---------------------------------------------------------------------------
// K3: ctx_global[b,c] = gelu(mean over H,W of ctx)  (ctx bf16 -> cglob fp32)
// ---------------------------------------------------------------------------
__global__ __launch_bounds__(256) void ctx_mean_gelu(
    const ushort_t* __restrict__ ctx, float* __restrict__ cglob)
{
    const int b  = blockIdx.y;
    const int c4 = blockIdx.x << 2;
    const ushort_t* p = ctx + (size_t)b * HW_ * C_ + c4;
    float sx = 0.f, sy = 0.f, sz = 0.f, sw = 0.f;
    for (int i = threadIdx.x; i < HW_; i += 256) {
        const ushort4 v = *(const ushort4*)(p + (size_t)i * C_);
        sx += b2f(v.x); sy += b2f(v.y); sz += b2f(v.z); sw += b2f(v.w);
    }
    __shared__ float4 red[256];
    red[threadIdx.x] = make_float4(sx, sy, sz, sw);
    __syncthreads();
    for (int off = 128; off > 0; off >>= 1) {
        if (threadIdx.x < off) {
            float4 a = red[threadIdx.x];
            const float4 c = red[threadIdx.x + off];
            a.x += c.x; a.y += c.y; a.z += c.z; a.w += c.w;
            red[threadIdx.x] = a;
        }
        __syncthreads();
    }
    if (threadIdx.x == 0) {
        const float inv = 1.0f / (float)HW_;
        const float4 m = red[0];
        float4 o;
        o.x = gelu_f(m.x * inv); o.y = gelu_f(m.y * inv);
        o.z = gelu_f(m.z * inv); o.w = gelu_f(m.w * inv);
        *(float4*)(cglob + b * C_ + c4) = o;
    }
}

// ---------------------------------------------------------------------------
// K4: mod = (ctx_all + cglob*g3) @ Wh + bh ; q = x @ Wf[:, :C] + bf[:C] ;
//     x_out = q * mod ; LayerNorm -> xln (bf16)
// ---------------------------------------------------------------------------
__global__ __launch_bounds__(256) void modq_ln(
    const ushort_t* __restrict__ ctx_all, const float* __restrict__ cglob,
    const float* __restrict__ gates, const float* __restrict__ x,
    const float* __restrict__ Wf, const float* __restrict__ bf,
    const float* __restrict__ Wh, const float* __restrict__ bh,
    const float* __restrict__ gamma, const float* __restrict__ beta,
    ushort_t* __restrict__ xln)
{
    __shared__ float smem[12288 + 128];
    float (*As)[64]  = (float(*)[64])smem;             // 64 x 64
    float (*Bs)[128] = (float(*)[128])(smem + 4096);   // 64 x 128
    float (*xs)[132] = (float(*)[132])smem;            // 64 x 132 (reuse)
    float* mu_s = smem + 12288;
    float* rs_s = smem + 12288 + 64;

    const int tid  = threadIdx.x;
    const int tok0 = blockIdx.x * 64;
    const int bidx = tok0 / HW_;
    const int t    = tid & 63;
    const int k4   = (tid >> 6) << 2;
    const int tx   = tid & 15, ty = tid >> 4;
    const float g3 = gates[(size_t)(tok0 + t) * 4 + 3];

    float acc_m[32] = {};
    float acc_q[32] = {};

    // ---- pass A: modulator GEMM (A = ctx_all + cglob*g3, B = Wh) ----
    for (int kc = 0; kc < C_; kc += 64) {
        __syncthreads();
        {
            const ushort_t* ap = ctx_all + (size_t)(tok0 + t) * C_ + kc;
            const float* gp = cglob + bidx * C_ + kc;
            #pragma unroll
            for (int kk = k4; kk < 64; kk += 16) {
                const ushort4 u = *(const ushort4*)(ap + kk);
                const float4 cg = *(const float4*)(gp + kk);
                As[kk+0][t] = b2f(u.x) + cg.x * g3;
                As[kk+1][t] = b2f(u.y) + cg.y * g3;
                As[kk+2][t] = b2f(u.z) + cg.z * g3;
                As[kk+3][t] = b2f(u.w) + cg.w * g3;
            }
        }
        {
            const int n4b = (tid & 31) << 2;
            const int kr  = tid >> 5;
            #pragma unroll
            for (int kk = kr; kk < 64; kk += 8)
                *(float4*)&Bs[kk][n4b] = *(const float4*)(Wh + (size_t)(kc + kk) * C_ + n4b);
        }
        __syncthreads();
        #pragma unroll 4
        for (int k = 0; k < 64; ++k) {
            const float4 a  = *(const float4*)&As[k][ty << 2];
            const float4 b0 = *(const float4*)&Bs[k][tx << 2];
            const float4 b1 = *(const float4*)&Bs[k][64 + (tx << 2)];
            const float av[4] = {a.x, a.y, a.z, a.w};
            const float bv[8] = {b0.x, b0.y, b0.z, b0.w, b1.x, b1.y, b1.z, b1.w};
            #pragma unroll
            for (int i = 0; i < 4; ++i)
                #pragma unroll
                for (int j = 0; j < 8; ++j)
                    acc_m[i*8+j] += av[i] * bv[j];
        }
    }

    // ---- pass B: q GEMM (A = x, B = Wf cols 0..127, row stride 260) ----
    for (int kc = 0; kc < C_; kc += 64) {
        __syncthreads();
        {
            const float* ap = x + (size_t)(tok0 + t) * C_ + kc;
            #pragma unroll
            for (int kk = k4; kk < 64; kk += 16) {
                const float4 v = *(const float4*)(ap + kk);
                As[kk+0][t] = v.x; As[kk+1][t] = v.y;
                As[kk+2][t] = v.z; As[kk+3][t] = v.w;
            }
        }
        {
            const int n4b = (tid & 31) << 2;
            const int kr  = tid >> 5;
            #pragma unroll
            for (int kk = kr; kk < 64; kk += 8)
                *(float4*)&Bs[kk][n4b] = *(const float4*)(Wf + (size_t)(kc + kk) * NOUT + n4b);
        }
        __syncthreads();
        #pragma unroll 4
        for (int k = 0; k < 64; ++k) {
            const float4 a  = *(const float4*)&As[k][ty << 2];
            const float4 b0 = *(const float4*)&Bs[k][tx << 2];
            const float4 b1 = *(const float4*)&Bs[k][64 + (tx << 2)];
            const float av[4] = {a.x, a.y, a.z, a.w};
            const float bv[8] = {b0.x, b0.y, b0.z, b0.w, b1.x, b1.y, b1.z, b1.w};
            #pragma unroll
            for (int i = 0; i < 4; ++i)
                #pragma unroll
                for (int j = 0; j < 8; ++j)
                    acc_q[i*8+j] += av[i] * bv[j];
        }
    }
    __syncthreads();   // smem becomes xs

    {   // x_out = (q)*(mod), stash into xs
        const int n1 = tx << 2, n2 = 64 + (tx << 2);
        const float4 bh1 = *(const float4*)(bh + n1);
        const float4 bh2 = *(const float4*)(bh + n2);
        const float4 bf1 = *(const float4*)(bf + n1);
        const float4 bf2 = *(const float4*)(bf + n2);
        #pragma unroll
        for (int i = 0; i < 4; ++i) {
            const int m = (ty << 2) + i;
            xs[m][n1+0] = (acc_q[i*8+0] + bf1.x) * (acc_m[i*8+0] + bh1.x);
            xs[m][n1+1] = (acc_q[i*8+1] + bf1.y) * (acc_m[i*8+1] + bh1.y);
            xs[m][n1+2] = (acc_q[i*8+2] + bf1.z) * (acc_m[i*8+2] + bh1.z);
            xs[m][n1+3] = (acc_q[i*8+3] + bf1.w) * (acc_m[i*8+3] + bh1.w);
            xs[m][n2+0] = (acc_q[i*8+4] + bf2.x) * (acc_m[i*8+4] + bh2.x);
            xs[m][n2+1] = (acc_q[i*8+5] + bf2.y) * (acc_m[i*8+5] + bh2.y);
            xs[m][n2+2] = (acc_q[i*8+6] + bf2.z) * (acc_m[i*8+6] + bh2.z);
            xs[m][n2+3] = (acc_q[i*8+7] + bf2.w) * (acc_m[i*8+7] + bh2.w);
        }
    }
    __syncthreads();

    if (tid < 64) {
        float s = 0.f, s2 = 0.f;
        #pragma unroll
        for (int c = 0; c < C_; c += 4) {
            const float4 v = *(const float4*)&xs[tid][c];
            s  += v.x + v.y + v.z + v.w;
            s2 += v.x*v.x + v.y*v.y + v.z*v.z + v.w*v.w;
        }
        const float mu  = s * (1.0f / 128.0f);
        const float var = s2 * (1.0f / 128.0f) - mu * mu;
        mu_s[tid] = mu;
        rs_s[tid] = rsqrtf(var + 0.001f);
    }
    __syncthreads();

    {   // normalize + affine -> xln (bf16)
        const int tt = tid >> 2;
        const int c0 = (tid & 3) << 5;
        const float mu = mu_s[tt], rs = rs_s[tt];
        ushort_t* op = xln + (size_t)(tok0 + tt) * C_;
        #pragma unroll
        for (int j = 0; j < 8; ++j) {
            const int c = c0 + (j << 2);
            const float4 v  = *(const float4*)&xs[tt][c];
            const float4 gm = *(const float4*)(gamma + c);
            const float4 bt = *(const float4*)(beta + c);
            ushort4 o;
            o.x = f2b((v.x - mu) * rs * gm.x + bt.x);
            o.y = f2b((v.y - mu) * rs * gm.y + bt.y);
            o.z = f2b((v.z - mu) * rs * gm.z + bt.z);
            o.w = f2b((v.w - mu) * rs * gm.w + bt.w);
            *(ushort4*)(op + c) = o;
        }
    }
}

// ---------------------------------------------------------------------------
// K5: out = xln @ Wp + bp   (xln bf16, out fp32)
// ---------------------------------------------------------------------------
__global__ __launch_bounds__(256) void gemm_out(
    const ushort_t* __restrict__ xln, const float* __restrict__ Wp,
    const float* __restrict__ bp, float* __restrict__ out)
{
    __shared__ float smem[12288];
    float (*As)[64]  = (float(*)[64])smem;
    float (*Bs)[128] = (float(*)[128])(smem + 4096);

    const int tid  = threadIdx.x;
    const int tok0 = blockIdx.x * 64;
    const int t    = tid & 63;
    const int k4   = (tid >> 6) << 2;
    const int tx   = tid & 15, ty = tid >> 4;

    float acc[32] = {};
    for (int kc = 0; kc < C_; kc += 64) {
        __syncthreads();
        {
            const ushort_t* ap = xln + (size_t)(tok0 + t) * C_ + kc;
            #pragma unroll
            for (int kk = k4; kk < 64; kk += 16) {
                const ushort4 u = *(const ushort4*)(ap + kk);
                As[kk+0][t] = b2f(u.x); As[kk+1][t] = b2f(u.y);
                As[kk+2][t] = b2f(u.z); As[kk+3][t] = b2f(u.w);
            }
        }
        {
            const int n4b = (tid & 31) << 2;
            const int kr  = tid >> 5;
            #pragma unroll
            for (int kk = kr; kk < 64; kk += 8)
                *(float4*)&Bs[kk][n4b] = *(const float4*)(Wp + (size_t)(kc + kk) * C_ + n4b);
        }
        __syncthreads();
        #pragma unroll 4
        for (int k = 0; k < 64; ++k) {
            const float4 a  = *(const float4*)&As[k][ty << 2];
            const float4 b0 = *(const float4*)&Bs[k][tx << 2];
            const float4 b1 = *(const float4*)&Bs[k][64 + (tx << 2)];
            const float av[4] = {a.x, a.y, a.z, a.w};
            const float bv[8] = {b0.x, b0.y, b0.z, b0.w, b1.x, b1.y, b1.z, b1.w};
            #pragma unroll
            for (int i = 0; i < 4; ++i)
                #pragma unroll
                for (int j = 0; j < 8; ++j)
                    acc[i*8+j] += av[i] * bv[j];
        }
    }

    const int n1 = tx << 2, n2 = 64 + (tx << 2);
    const float4 b1 = *(const float4*)(bp + n1);
    const float4 b2 = *(const float4*)(bp + n2);
    #pragma unroll
    for (int i = 0; i < 4; ++i) {
        const int token = tok0 + (ty << 2) + i;
        float4 r1, r2;
        r1.x = acc[i*8+0] + b1.x; r1.y = acc[i*8+1] + b1.y;
        r1.z = acc[i*8+2] + b1.z; r1.w = acc[i*8+3] + b1.w;
        r2.x = acc[i*8+4] + b2.x; r2.y = acc[i*8+5] + b2.y;
        r2.z = acc[i*8+6] + b2.z; r2.w = acc[i*8+7] + b2.w;
        *(float4*)(out + (size_t)token * C_ + n1) = r1;
        *(float4*)(out + (size_t)token * C_ + n2) = r2;
    }
}

// ---------------------------------------------------------------------------
extern "C" void kernel_launch(void* const* d_in, const int* in_sizes, int n_in,
                              void* d_out, int out_size, void* d_ws, size_t ws_size,
                              hipStream_t stream) {
    const float* x     = (const float*)d_in[0];
    const float* Wf    = (const float*)d_in[1];
    const float* bf    = (const float*)d_in[2];
    const float* Wh    = (const float*)d_in[3];
    const float* bh    = (const float*)d_in[4];
    const float* gamma = (const float*)d_in[5];
    const float* beta  = (const float*)d_in[6];
    const float* Wp    = (const float*)d_in[7];
    const float* bp    = (const float*)d_in[8];
    const float* k0    = (const float*)d_in[9];
    const float* k1    = (const float*)d_in[10];
    const float* k2    = (const float*)d_in[11];
    float* out = (float*)d_out;

    const size_t NC = (size_t)NTOK * C_;
    ushort_t* P0  = (ushort_t*)d_ws;          // ctx ping
    ushort_t* P1  = P0 + NC;                  // ctx pong
    ushort_t* ACC = P1 + NC;                  // ctx_all
    float* gates  = (float*)(ACC + NC);
    float* cglob  = gates + (size_t)NTOK * 4;
    // total: 3*NC*2 + NTOK*16 + B*C*4 = 115.6 MB

    gemm_ctx_gates<<<NTOK / 64, 256, 0, stream>>>(x, Wf, bf, P0, gates);
    dwconv_k<3><<<NTOK * 32 / 256, 256, 0, stream>>>(P0, k0, gates, P1, ACC, 0);
    dwconv_k<5><<<NTOK * 32 / 256, 256, 0, stream>>>(P1, k1, gates, P0, ACC, 1);
    dwconv_k<7><<<NTOK * 32 / 256, 256, 0, stream>>>(P0, k2, gates, P1, ACC, 2);
    ctx_mean_gelu<<<dim3(C_ / 4, B_), 256, 0, stream>>>(P1, cglob);
    modq_ln<<<NTOK / 64, 256, 0, stream>>>(ACC, cglob, gates, x, Wf, bf, Wh, bh, gamma, beta, P0);
    gemm_out<<<NTOK / 64, 256, 0, stream>>>(P0, Wp, bp, out);
}